// Round 1
// baseline (1571.142 us; speedup 1.0000x reference)
//
#include <hip/hip_runtime.h>
#include <stdint.h>

#define R_NODES 256
#define M_SAMP  512
#define S_STEPS 512
#define OUT_N   10

// ---------------- layout detection for bool inputs ----------------
// If bools were uploaded as int32, byte (4f+1) of every element is 0.
// If uploaded as uint8, ~half those bytes are 1.  flag=1 => uint8 layout.
__global__ void detect_layout(const uint8_t* __restrict__ x, int* __restrict__ flag) {
    __shared__ int any;
    if (threadIdx.x == 0) any = 0;
    __syncthreads();
    int acc = 0;
    for (int i = 0; i < 64; ++i)
        acc |= x[(size_t)(threadIdx.x * 64 + i) * 4 + 1];
    if (acc) atomicOr(&any, 1);
    __syncthreads();
    if (threadIdx.x == 0) *flag = any ? 1 : 0;
}

// ---------------- pack x bits: one uint32 per (m,s) ----------------
__global__ void pack_x(const uint8_t* __restrict__ x, const int* __restrict__ flag,
                       uint32_t* __restrict__ xp) {
    const int stride = (*flag) ? 1 : 4;
    const int f = blockIdx.x * blockDim.x + threadIdx.x;      // element idx, M*S*32 total
    const int val = x[(size_t)f * stride];
    const uint64_t mask = __ballot(val != 0);
    const int lane = threadIdx.x & 63;
    if ((lane & 31) == 0) {
        uint32_t w = (lane & 32) ? (uint32_t)(mask >> 32) : (uint32_t)mask;
        xp[f >> 5] = w;
    }
}

// ---------------- build byte-chunk partial-sum table ----------------
// T2[c][v][j] = sum_{b in v} primes[c*8+b] * W_res[j][c*8+b], uint16 (max ~12.8K)
__global__ void build_T2(const uint8_t* __restrict__ wres, const int* __restrict__ primes,
                         const int* __restrict__ flag, uint16_t* __restrict__ T2) {
    const int v = blockIdx.x;          // 0..255 byte value
    const int c = blockIdx.y;          // 0..31 chunk
    const int j = threadIdx.x;         // 0..255 node
    const int stride = (*flag) ? 1 : 4;
    int sum = 0;
#pragma unroll
    for (int b = 0; b < 8; ++b) {
        if ((v >> b) & 1) {
            const int k = c * 8 + b;
            if (wres[(size_t)(j * 256 + k) * stride]) sum += primes[k];
        }
    }
    T2[(size_t)(c * 256 + v) * 256 + j] = (uint16_t)sum;
}

// ---------------- bit-pack the LUT: 256MB int32 -> 8MB bits ----------------
__global__ void pack_lut(const int* __restrict__ lut, uint64_t* __restrict__ lp) {
    const int j = blockIdx.y;                 // row 0..255
    const int wbase = blockIdx.x * 256;       // 16 blocks per row, 256 words each
    const int wid = threadIdx.x >> 6;
    const int lane = threadIdx.x & 63;
    const int* row = lut + (size_t)j * 262144;
#pragma unroll 4
    for (int w = wbase + wid; w < wbase + 256; w += 4) {
        const int val = row[w * 64 + lane];
        const uint64_t mask = __ballot(val != 0);
        if (lane == 0) lp[(size_t)j * 4096 + w] = mask;
    }
}

// ---------------- main reservoir scan: one block per sample ----------------
__global__ __launch_bounds__(256) void reservoir_main(
    const uint32_t* __restrict__ xp, const uint16_t* __restrict__ T2,
    const uint64_t* __restrict__ lp, const int* __restrict__ input_nodes,
    const uint8_t* __restrict__ init_res, const int* __restrict__ flag,
    const float* __restrict__ rW, const float* __restrict__ rb,
    float* __restrict__ out)
{
    const int m = blockIdx.x;
    const int j = threadIdx.x;
    const int wid = j >> 6;
    const int lane = j & 63;
    __shared__ uint64_t lmask[4];
    __shared__ float lout[OUT_N];

    const int stride = (*flag) ? 1 : 4;
    int slot = -1;
#pragma unroll
    for (int i = 0; i < 32; ++i)
        if (input_nodes[i] == j) slot = i;

    int v = init_res[(size_t)j * stride] ? 1 : 0;
    const uint64_t* lrow = lp + (size_t)j * 4096;
    const uint32_t* xrow = xp + m * S_STEPS;
    const uint16_t* tj = T2 + j;

    for (int s = 0; s < S_STEPS; ++s) {
        const uint32_t xw = xrow[s];
        if (slot >= 0) v = (xw >> slot) & 1;
        const uint64_t bal = __ballot(v != 0);
        if (lane == 0) lmask[wid] = bal;
        __syncthreads();
        const uint64_t m0 = lmask[0], m1 = lmask[1], m2 = lmask[2], m3 = lmask[3];
        __syncthreads();   // protect lmask from next iteration's overwrite
        int idx = 0;
#pragma unroll
        for (int c = 0; c < 8; ++c)
            idx += tj[((c     ) * 256 + (int)((m0 >> (c * 8)) & 0xFF)) * 256];
#pragma unroll
        for (int c = 0; c < 8; ++c)
            idx += tj[((c +  8) * 256 + (int)((m1 >> (c * 8)) & 0xFF)) * 256];
#pragma unroll
        for (int c = 0; c < 8; ++c)
            idx += tj[((c + 16) * 256 + (int)((m2 >> (c * 8)) & 0xFF)) * 256];
#pragma unroll
        for (int c = 0; c < 8; ++c)
            idx += tj[((c + 24) * 256 + (int)((m3 >> (c * 8)) & 0xFF)) * 256];
        v = (int)((lrow[idx >> 6] >> (idx & 63)) & 1);
    }

    // readout: out[m][o] = b[o] + sum_j v_j * W[o][j]
    if (j < OUT_N) lout[j] = 0.f;
    __syncthreads();
#pragma unroll
    for (int o = 0; o < OUT_N; ++o) {
        float contrib = v ? rW[o * R_NODES + j] : 0.f;
        for (int off = 32; off > 0; off >>= 1)
            contrib += __shfl_down(contrib, off, 64);
        if (lane == 0) atomicAdd(&lout[o], contrib);
    }
    __syncthreads();
    if (j < OUT_N) out[m * OUT_N + j] = lout[j] + rb[j];
}

extern "C" void kernel_launch(void* const* d_in, const int* in_sizes, int n_in,
                              void* d_out, int out_size, void* d_ws, size_t ws_size,
                              hipStream_t stream) {
    const uint8_t* x        = (const uint8_t*)d_in[0];   // bool [M,S,D,B]
    const int* input_nodes  = (const int*)d_in[1];       // int32 [32]
    const int* lut          = (const int*)d_in[2];       // int32 [256, 2^18]
    const uint8_t* wres     = (const uint8_t*)d_in[3];   // bool [256,256]
    const int* primes       = (const int*)d_in[4];       // int32 [256]
    const uint8_t* init_res = (const uint8_t*)d_in[5];   // bool [256]
    const float* rW         = (const float*)d_in[6];     // f32 [10,256]
    const float* rb         = (const float*)d_in[7];     // f32 [10]
    float* out              = (float*)d_out;             // f32 [512,10]

    uint8_t* ws = (uint8_t*)d_ws;
    int*      flag = (int*)ws;                                        // 4 B
    uint32_t* xp   = (uint32_t*)(ws + 4096);                          // 1 MB
    uint16_t* T2   = (uint16_t*)(ws + 4096 + 1048576);                // 4 MB
    uint64_t* lp   = (uint64_t*)(ws + 4096 + 1048576 + 4194304);      // 8 MB

    detect_layout<<<1, 256, 0, stream>>>(x, flag);
    pack_x<<<(M_SAMP * S_STEPS * 32) / 256, 256, 0, stream>>>(x, flag, xp);
    build_T2<<<dim3(256, 32), 256, 0, stream>>>(wres, primes, flag, T2);
    pack_lut<<<dim3(16, 256), 256, 0, stream>>>(lut, lp);
    reservoir_main<<<M_SAMP, 256, 0, stream>>>(xp, T2, lp, input_nodes, init_res,
                                               flag, rW, rb, out);
}